// Round 8
// baseline (111.180 us; speedup 1.0000x reference)
//
#include <hip/hip_runtime.h>

// OPU via MFMA. R23 = SINGLE kernel, ZERO LDS staging, ZERO workspace, ZERO combine:
// register-direct raw loads + in-register table split, quadrant-per-wave.
// R22 post-mortem (97.5; fused 41.8us, MfmaUtil 11%, VALU 27%): LDS-staged fusion put
// CONV between barriers on the critical path. R17's main stalls 85% because each chunk
// has only ~40 VALU-cyc to cover 300-500cyc L2 latency; presplit's 12us of conversion
// work is exactly the missing latency filler. R23 moves the split into the main loop's
// load shadow: wave owns a 32x32 quadrant (R18-verified C/D mapping) over full K;
// per chunk loads RAW f32 (same bytes as split-u16: f32 == hi/lo pair), converts via
// the 256-entry packed tables in-register (~72 VALU + 16 gathers per chunk = 5x R17's
// latency cover), 3-MFMA chain, biased quant. No barriers after table build. Gather
// bank check: idx = oct*128 + e*16 + xi -> bank (e&1)*16+xi, <=2 distinct addr/bank
// (oct 0/1) = 2-way = free (m136). A-frag reads are per-lane 32B at 4KB row stride
// (uncoalesced instr) but a chunk's A slice is 4KB -> L1 re-coalesces across chunks.
// Removed: presplit kernel (~12us), one launch gap (~3us), 24MB ws round-trip, fill
// budget unchanged (harness poisons ws regardless; ~44us fixed floor in dur_us).
// Carried: biased-magic quant (res at 1.5*2^23: fp32 RNE in res+=acc IS the per-chunk
// ADC rint; swing <=1120 << 4.19M margin), bit-identical split tables (X: fl(x+vlut);
// W: fl(fl(w+wlut)/16) exact pow2 fold), AlBl dropped (|err|<=4e-6), clip provably
// dead (|mm/16|<=68.9<127.5), per-XCD swizzle, 4-buffer literal-indexed depth-3
// prefetch (R7 lesson: no ring indexing). R16 lesson: no coop launch under capture.

typedef unsigned int u32;
typedef unsigned short u16;
typedef _Float16 f16x8 __attribute__((ext_vector_type(8)));
typedef float f32x16 __attribute__((ext_vector_type(16)));

#define N_TOT 1024
#define K_TOT 1024
#define RBIAS 12582912.0f  // 1.5 * 2^23: fp32 ulp = 1.0, integer-grid RNE in the add

__device__ __forceinline__ u32 split_pack(float a) {
  _Float16 h = (_Float16)a;              // v_cvt_f16_f32 (RNE)
  _Float16 l = (_Float16)(a - (float)h); // exact fp32 sub then RNE
  return (u32)__builtin_bit_cast(u16, h) | ((u32)__builtin_bit_cast(u16, l) << 16);
}
__device__ __forceinline__ u32 pk_lo(u32 a, u32 b) { return (a & 0xffffu) | (b << 16); }
__device__ __forceinline__ u32 pk_hi(u32 a, u32 b) { return (a >> 16) | (b & 0xffff0000u); }

__global__ __launch_bounds__(256, 2) void opu_fused(
    const float* __restrict__ x, const float* __restrict__ w,
    const float* __restrict__ vl, const float* __restrict__ wl,
    float* __restrict__ out)
{
  __shared__ u32 tabX[256];   // packed hi/lo of fl((xi-8) + vl[j][xi])
  __shared__ u32 tabW[256];   // packed hi/lo of fl(((wi-8) + wl[j][wi]) * 1/16)

  const int tid  = threadIdx.x;
  const int wave = tid >> 6;
  const int lane = tid & 63;
  const int oct  = lane >> 5;
  const int ll   = lane & 31;
  const int rg   = wave >> 1;   // owned A row-group (32 rows)
  const int ng   = wave & 1;    // owned B col-group (32 cols)

  const int bx   = blockIdx.x;
  const int nblk = (bx & 1) + 2 * ((bx >> 3) & 7);   // 0..15  per-XCD swizzle
  const int mblk = ((bx >> 1) & 3) + 4 * (bx >> 6);  // 0..31

  // A fragment (32x32x16 f16): lane -> row = ll, k = oct*8 + e  => 8 contiguous floats
  const float* pA = x + (size_t)(mblk * 64 + rg * 32 + ll) * K_TOT + oct * 8;
  // B fragment: lane -> col = ll, k = oct*8 + e  => 8 row-strided floats
  const float* pB = w + (size_t)(oct * 8) * N_TOT + nblk * 64 + ng * 32 + ll;

  const int tb = oct * 128;    // table row base: j = oct*8 + e  ->  j*16 = tb + e*16

  // ---- raw chunk buffers: 4 sets (depth-3 prefetch), literal-indexed only ----
  float a0[8], b0[8], a1[8], b1[8], a2[8], b2[8], a3[8], b3[8];

#define RL(da, db, ch)                                                   \
  do {                                                                   \
    const float4 _x0 = *(const float4*)(pA + (size_t)(ch) * 16);         \
    const float4 _x1 = *(const float4*)(pA + (size_t)(ch) * 16 + 4);     \
    (da)[0] = _x0.x; (da)[1] = _x0.y; (da)[2] = _x0.z; (da)[3] = _x0.w;  \
    (da)[4] = _x1.x; (da)[5] = _x1.y; (da)[6] = _x1.z; (da)[7] = _x1.w;  \
    (db)[0] = pB[(size_t)((ch) * 16 + 0) * N_TOT];                       \
    (db)[1] = pB[(size_t)((ch) * 16 + 1) * N_TOT];                       \
    (db)[2] = pB[(size_t)((ch) * 16 + 2) * N_TOT];                       \
    (db)[3] = pB[(size_t)((ch) * 16 + 3) * N_TOT];                       \
    (db)[4] = pB[(size_t)((ch) * 16 + 4) * N_TOT];                       \
    (db)[5] = pB[(size_t)((ch) * 16 + 5) * N_TOT];                       \
    (db)[6] = pB[(size_t)((ch) * 16 + 6) * N_TOT];                       \
    (db)[7] = pB[(size_t)((ch) * 16 + 7) * N_TOT];                       \
  } while (0)

  float res[16];
#pragma unroll
  for (int i = 0; i < 16; ++i) res[i] = RBIAS;  // biased: each add RNE-rounds to int grid
  const f32x16 fzero = {};

  // In-register split + 3-MFMA + biased quant (per-chunk ADC rint in the add).
#define PROC(a, b)                                                                \
  do {                                                                            \
    u32 tA[8], tB[8];                                                             \
    _Pragma("unroll")                                                             \
    for (int e = 0; e < 8; ++e) {                                                 \
      tA[e] = tabX[tb + e * 16 + (int)((a)[e] + 8.0f)];                           \
      tB[e] = tabW[tb + e * 16 + (int)((b)[e] + 8.0f)];                           \
    }                                                                             \
    const uint4 uAH = make_uint4(pk_lo(tA[0], tA[1]), pk_lo(tA[2], tA[3]),        \
                                 pk_lo(tA[4], tA[5]), pk_lo(tA[6], tA[7]));       \
    const uint4 uAL = make_uint4(pk_hi(tA[0], tA[1]), pk_hi(tA[2], tA[3]),        \
                                 pk_hi(tA[4], tA[5]), pk_hi(tA[6], tA[7]));       \
    const uint4 uBH = make_uint4(pk_lo(tB[0], tB[1]), pk_lo(tB[2], tB[3]),        \
                                 pk_lo(tB[4], tB[5]), pk_lo(tB[6], tB[7]));       \
    const uint4 uBL = make_uint4(pk_hi(tB[0], tB[1]), pk_hi(tB[2], tB[3]),        \
                                 pk_hi(tB[4], tB[5]), pk_hi(tB[6], tB[7]));       \
    const f16x8 Ah = __builtin_bit_cast(f16x8, uAH);                              \
    const f16x8 Al = __builtin_bit_cast(f16x8, uAL);                              \
    const f16x8 Bh = __builtin_bit_cast(f16x8, uBH);                              \
    const f16x8 Bl = __builtin_bit_cast(f16x8, uBL);                              \
    f32x16 acc = __builtin_amdgcn_mfma_f32_32x32x16_f16(Ah, Bh, fzero, 0, 0, 0);  \
    acc = __builtin_amdgcn_mfma_f32_32x32x16_f16(Al, Bh, acc, 0, 0, 0);           \
    acc = __builtin_amdgcn_mfma_f32_32x32x16_f16(Ah, Bl, acc, 0, 0, 0);           \
    _Pragma("unroll")                                                             \
    for (int i = 0; i < 16; ++i) res[i] += acc[i];                                \
  } while (0)

#define CL63(v) ((v) > 63 ? 63 : (v))

  // ---- prologue: issue first raw loads, build tables, one barrier ----
  RL(a0, b0, 0); RL(a1, b1, 1); RL(a2, b2, 2);
  {
    const int j = tid >> 4, xi = tid & 15;
    const float base = (float)(xi - 8);
    tabX[tid] = split_pack(base + vl[j * 16 + xi]);
    tabW[tid] = split_pack((base + wl[j * 16 + xi]) * 0.0625f);
  }
  __syncthreads();   // tables ready; raw loads still in flight

  // ---- main: 64 chunks, depth-3 prefetch, no barriers ----
#pragma unroll 1
  for (int it = 0; it < 16; ++it) {
    const int ch = it * 4;
    RL(a3, b3, ch + 3);          PROC(a0, b0);
    RL(a0, b0, CL63(ch + 4));    PROC(a1, b1);   // tail prefetches redundantly reload 63
    RL(a1, b1, CL63(ch + 5));    PROC(a2, b2);
    RL(a2, b2, CL63(ch + 6));    PROC(a3, b3);
  }

  // ---- direct per-wave store (R18-verified 32x32 C/D mapping) ----
  float* op = out + (size_t)(mblk * 64 + rg * 32 + 4 * oct) * N_TOT
                  + nblk * 64 + ng * 32 + ll;
#pragma unroll
  for (int i = 0; i < 16; ++i) {
    const int r = (i & 3) + 8 * (i >> 2);
    op[(size_t)r * N_TOT] = (res[i] - RBIAS) * 16.0f;
  }
}

extern "C" void kernel_launch(void* const* d_in, const int* in_sizes, int n_in,
                              void* d_out, int out_size, void* d_ws, size_t ws_size,
                              hipStream_t stream)
{
  const float* input  = (const float*)d_in[0];
  const float* weight = (const float*)d_in[1];
  const float* vmap   = (const float*)d_in[2];
  const float* wmap   = (const float*)d_in[3];
  float* out = (float*)d_out;
  (void)d_ws; (void)ws_size;   // no workspace: split fused into registers

  opu_fused<<<512, 256, 0, stream>>>(input, weight, vmap, wmap, out);
}

// Round 9
// 87.800 us; speedup vs baseline: 1.2663x; 1.2663x over previous
//
#include <hip/hip_runtime.h>

// OPU via MFMA. R24 = main BYTE-IDENTICAL to R17 (known best, 85.9) + presplit v2:
// 1024 blocks (4/CU, was 2/CU), balanced W fold, 8KB LDS image.
// R23 post-mortem (111.2; fused 52.9us, VGPR=56): register-direct fusion never had its
// prefetch -- compiler sank loads to uses (56 regs vs ~150 needed), plus x22 conversion
// redundancy. Fusion dead (R22 41.9, R23 52.9 vs presplit+main 30.3).
// Ledger via R17/R22 subtraction: dur = fill 44.5 (harness ws poison, fixed) + ~11
// fixed rep overhead + kernels 30.3 (presplit ~12 + gap + main ~17-20). Main's old
// 112VGPR+64AGPR says its pipeline was real -> near its ~13us floor (6 MFMA + 7 VALU),
// consistent with R14/R21 interior changes all neutral. Never-optimized piece:
// presplit ~12us vs ~6us memory floor at only 2 blocks/CU + serial LDS round trip.
// R24 presplit: 1024 blocks x 256thr = 4/CU; X = 2 chunks/block (8KB image); W item
// per thread<128 of EVERY block (g2 = b*128+tid, bijective over 131072, balanced).
// All math bit-identical: same tables, same j = k-in-chunk mapping, same pack order,
// same global layouts (verified index-by-index vs R17).
// Carried: biased-magic quant (res at 1.5*2^23: fp32 RNE in res+=acc IS the per-chunk
// ADC rint; swing <=1120 << 4.19M), merged-plane 4KB pages, AlBl dropped (|err|<=4e-6),
// clip provably dead, per-XCD swizzle, 4-step combine, x16 store.
// R16 lesson: no coop launch under graph capture. R7 lesson: literal-indexed buffers.

typedef unsigned int u32;
typedef unsigned short u16;
typedef _Float16 f16x8 __attribute__((ext_vector_type(8)));
typedef float f32x16 __attribute__((ext_vector_type(16)));

#define M_TOT 2048
#define N_TOT 1024
#define K_TOT 1024
#define RBIAS 12582912.0f  // 1.5 * 2^23: fp32 ulp = 1.0, integer-grid RNE in the add

__device__ __forceinline__ u32 split_pack(float a) {
  _Float16 h = (_Float16)a;              // v_cvt_f16_f32 (RNE)
  _Float16 l = (_Float16)(a - (float)h); // exact fp32 sub then RNE
  return (u32)__builtin_bit_cast(u16, h) | ((u32)__builtin_bit_cast(u16, l) << 16);
}
__device__ __forceinline__ u32 pk_lo(u32 a, u32 b) { return (a & 0xffffu) | (b << 16); }
__device__ __forceinline__ u32 pk_hi(u32 a, u32 b) { return (a >> 16) | (b & 0xffff0000u); }

__global__ __launch_bounds__(256) void presplit(
    const float* __restrict__ x, const float* __restrict__ w,
    const float* __restrict__ vl, const float* __restrict__ wl,
    u16* __restrict__ XHL, u16* __restrict__ WHL)
{
  __shared__ __align__(16) char lds[8192];   // X 2-chunk plane image
  __shared__ u32 tabX[256];
  __shared__ u32 tabW[256];

  const int b   = blockIdx.x;   // 0..1023
  const int tid = threadIdx.x;

  // ---- split tables: a = fl(x + vlut) (X) and fl(fl(w + wlut) * 1/16) (W) ----
  {
    const int j = tid >> 4, xi = tid & 15;
    const float base = (float)(xi - 8);
    tabX[tid] = split_pack(base + vl[j * 16 + xi]);
    tabW[tid] = split_pack((base + wl[j * 16 + xi]) * 0.0625f);
  }
  __syncthreads();

  // ---- W presplit: threads 0..127 of every block, one (ch, oct, n) item each ----
  if (tid < 128) {
    const int g2 = b * 128 + tid;           // 0..131071, bijective
    const int n  = g2 & 1023;
    const int co = g2 >> 10;                // 0..127 = (ch, oct)
    const int ch = co >> 1, oct = co & 1;
    const int nblk = n >> 6, ng = (n >> 5) & 1, n32 = n & 31;
    const float* wp = w + (size_t)(ch * 16 + oct * 8) * N_TOT + n;

    u32 hp[4], lp[4];
#pragma unroll
    for (int e2 = 0; e2 < 4; ++e2) {
      const int e = e2 * 2;
      const float w0 = wp[(size_t)e * N_TOT];
      const float w1 = wp[(size_t)(e + 1) * N_TOT];
      const u32 t0 = tabW[(oct * 8 + e) * 16 + (int)(w0 + 8.0f)];
      const u32 t1 = tabW[(oct * 8 + e + 1) * 16 + (int)(w1 + 8.0f)];
      hp[e2] = pk_lo(t0, t1);
      lp[e2] = pk_hi(t0, t1);
    }
    // chunk base (u16): (nblk*64+ch)*2048 ; layout hl*1024 + ng*512 + oct*256 + n32*8
    const size_t wb = (size_t)(nblk * 64 + ch) * 2048 + ng * 512 + oct * 256 + n32 * 8;
    *(uint4*)&WHL[wb]        = make_uint4(hp[0], hp[1], hp[2], hp[3]);
    *(uint4*)&WHL[wb + 1024] = make_uint4(lp[0], lp[1], lp[2], lp[3]);
  }

  // ---- X presplit: block = (mblk, chunk-pair); thread = (row, chl, k-half) ----
  {
    const int mblk = b >> 5, chg2 = b & 31;     // chunks chg2*2 + {0,1}
    const int row  = tid >> 2;                  // 0..63
    const int chl  = (tid >> 1) & 1;
    const int h    = tid & 1;                   // k-half == oct
    const int rg   = row >> 5, row32 = row & 31;

    const float* xp = x + (size_t)(mblk * 64 + row) * K_TOT + (chg2 * 2 + chl) * 16 + h * 8;
    const float4 x0 = *(const float4*)(xp);
    const float4 x1 = *(const float4*)(xp + 4);
    const float v[8] = { x0.x, x0.y, x0.z, x0.w, x1.x, x1.y, x1.z, x1.w };

    u32 hp[4], lp[4];
#pragma unroll
    for (int e2 = 0; e2 < 4; ++e2) {
      const int e = e2 * 2;
      const int j = h * 8 + e;                  // k-in-chunk index
      const u32 t0 = tabX[j * 16 + (int)(v[e] + 8.0f)];
      const u32 t1 = tabX[(j + 1) * 16 + (int)(v[e + 1] + 8.0f)];
      hp[e2] = pk_lo(t0, t1);
      lp[e2] = pk_hi(t0, t1);
    }

    // LDS image, exact global layout (bytes): chl*4096 + hl*2048 + rg*1024 + h*512 + row32*16
    char* basep = lds + chl * 4096 + rg * 1024 + h * 512 + row32 * 16;
    *(uint4*)(basep)        = make_uint4(hp[0], hp[1], hp[2], hp[3]);  // hi
    *(uint4*)(basep + 2048) = make_uint4(lp[0], lp[1], lp[2], lp[3]);  // lo
  }
  __syncthreads();

  // ---- coalesced dump: 8KB contiguous (2 chunk-planes) ----
  {
    const int mblk = b >> 5, chg2 = b & 31;
    const size_t gb = (size_t)(mblk * 64 + chg2 * 2) * 4096;  // bytes
    const int off = tid * 16;
    *(uint4*)((char*)XHL + gb + off)        = *(const uint4*)(lds + off);
    *(uint4*)((char*)XHL + gb + off + 4096) = *(const uint4*)(lds + off + 4096);
  }
}

__global__ __launch_bounds__(256, 2) void opu_main(
    const u16* __restrict__ XHL, const u16* __restrict__ WHL,
    float* __restrict__ out)
{
  __shared__ float cb[64 * 64];   // 16KB combine buffer

  const int tid  = threadIdx.x;
  const int wave = tid >> 6;      // k-slice: chunks [wave*16, wave*16+16)
  const int lane = tid & 63;
  const int oct  = lane >> 5;
  const int ll   = lane & 31;

  const int bx   = blockIdx.x;
  const int nblk = (bx & 1) + 2 * ((bx >> 3) & 7);   // 0..15
  const int mblk = ((bx >> 1) & 3) + 4 * (bx >> 6);  // 0..31

  // chunk stride 2048 u16 (4KB page: [hl][rg|ng][oct][32][k8])
  const u16* pA = XHL + (size_t)mblk * 131072 + (size_t)(wave * 16) * 2048 + lane * 8;
  const u16* pB = WHL + (size_t)nblk * 131072 + (size_t)(wave * 16) * 2048 + lane * 8;

  uint4 b0[8], b1[8];  // literal-indexed only (R7 lesson: %3 ring -> scratch spill)

#define LOADCH(dst, off)                                  \
  do {                                                    \
    (dst)[0] = *(const uint4*)(pA + (off));               \
    (dst)[1] = *(const uint4*)(pA + (off) + 512);         \
    (dst)[2] = *(const uint4*)(pA + (off) + 1024);        \
    (dst)[3] = *(const uint4*)(pA + (off) + 1536);        \
    (dst)[4] = *(const uint4*)(pB + (off));               \
    (dst)[5] = *(const uint4*)(pB + (off) + 512);         \
    (dst)[6] = *(const uint4*)(pB + (off) + 1024);        \
    (dst)[7] = *(const uint4*)(pB + (off) + 1536);        \
  } while (0)

  float res[4][16];
#pragma unroll
  for (int t = 0; t < 4; ++t)
#pragma unroll
    for (int i = 0; i < 16; ++i) res[t][i] = RBIAS;   // biased: each add RNE-rounds to int grid
  const f32x16 fzero = {};

  // Round-interleaved: 4 live accs; biased res += acc performs the per-chunk ADC rint.
#define COMPUTE(c)                                                                     \
  do {                                                                                 \
    const f16x8 Ah0 = __builtin_bit_cast(f16x8, (c)[0]);                               \
    const f16x8 Ah1 = __builtin_bit_cast(f16x8, (c)[1]);                               \
    const f16x8 Al0 = __builtin_bit_cast(f16x8, (c)[2]);                               \
    const f16x8 Al1 = __builtin_bit_cast(f16x8, (c)[3]);                               \
    const f16x8 Bh0 = __builtin_bit_cast(f16x8, (c)[4]);                               \
    const f16x8 Bh1 = __builtin_bit_cast(f16x8, (c)[5]);                               \
    const f16x8 Bl0 = __builtin_bit_cast(f16x8, (c)[6]);                               \
    const f16x8 Bl1 = __builtin_bit_cast(f16x8, (c)[7]);                               \
    f32x16 a0 = __builtin_amdgcn_mfma_f32_32x32x16_f16(Ah0, Bh0, fzero, 0, 0, 0);      \
    f32x16 a1 = __builtin_amdgcn_mfma_f32_32x32x16_f16(Ah0, Bh1, fzero, 0, 0, 0);      \
    f32x16 a2 = __builtin_amdgcn_mfma_f32_32x32x16_f16(Ah1, Bh0, fzero, 0, 0, 0);      \
    f32x16 a3 = __builtin_amdgcn_mfma_f32_32x32x16_f16(Ah1, Bh1, fzero, 0, 0, 0);      \
    a0 = __builtin_amdgcn_mfma_f32_32x32x16_f16(Al0, Bh0, a0, 0, 0, 0);                \
    a1 = __builtin_amdgcn_mfma_f32_32x32x16_f16(Al0, Bh1, a1, 0, 0, 0);                \
    a2 = __builtin_amdgcn_mfma_f32_32x32x16_f16(Al1, Bh0, a2, 0, 0, 0);                \
    a3 = __builtin_amdgcn_mfma_f32_32x32x16_f16(Al1, Bh1, a3, 0, 0, 0);                \
    a0 = __builtin_amdgcn_mfma_f32_32x32x16_f16(Ah0, Bl0, a0, 0, 0, 0);                \
    a1 = __builtin_amdgcn_mfma_f32_32x32x16_f16(Ah0, Bl1, a1, 0, 0, 0);                \
    a2 = __builtin_amdgcn_mfma_f32_32x32x16_f16(Ah1, Bl0, a2, 0, 0, 0);                \
    a3 = __builtin_amdgcn_mfma_f32_32x32x16_f16(Ah1, Bl1, a3, 0, 0, 0);                \
    _Pragma("unroll")                                                                  \
    for (int i = 0; i < 16; ++i) res[0][i] += a0[i];                                   \
    _Pragma("unroll")                                                                  \
    for (int i = 0; i < 16; ++i) res[1][i] += a1[i];                                   \
    _Pragma("unroll")                                                                  \
    for (int i = 0; i < 16; ++i) res[2][i] += a2[i];                                   \
    _Pragma("unroll")                                                                  \
    for (int i = 0; i < 16; ++i) res[3][i] += a3[i];                                   \
  } while (0)

  LOADCH(b0, 0);
#pragma unroll 1
  for (int c2 = 0; c2 < 8; ++c2) {
    const size_t o = (size_t)c2 * 4096;          // 2 chunks of 2048 u16
    LOADCH(b1, o + 2048);                        // prefetch odd chunk
    COMPUTE(b0);
    if (c2 < 7) LOADCH(b0, o + 4096);            // prefetch next even chunk
    COMPUTE(b1);
  }

  // ---- combine the 4 waves' k-slices through LDS (subtract bias -> exact ints) ----
#define CBIDX(mt, nt, i) ((((mt) * 32) + ((i & 3) + 8 * (i >> 2) + 4 * oct)) * 64 + (nt) * 32 + ll)
  if (wave == 0) {
#pragma unroll
    for (int mt = 0; mt < 2; ++mt)
#pragma unroll
      for (int nt = 0; nt < 2; ++nt)
#pragma unroll
        for (int i = 0; i < 16; ++i) cb[CBIDX(mt, nt, i)] = res[mt * 2 + nt][i] - RBIAS;
  }
  __syncthreads();
  if (wave == 1) {
#pragma unroll
    for (int mt = 0; mt < 2; ++mt)
#pragma unroll
      for (int nt = 0; nt < 2; ++nt)
#pragma unroll
        for (int i = 0; i < 16; ++i) cb[CBIDX(mt, nt, i)] += res[mt * 2 + nt][i] - RBIAS;
  }
  __syncthreads();
  if (wave == 2) {
#pragma unroll
    for (int mt = 0; mt < 2; ++mt)
#pragma unroll
      for (int nt = 0; nt < 2; ++nt)
#pragma unroll
        for (int i = 0; i < 16; ++i) cb[CBIDX(mt, nt, i)] += res[mt * 2 + nt][i] - RBIAS;
  }
  __syncthreads();
  if (wave == 3) {
#pragma unroll
    for (int mt = 0; mt < 2; ++mt)
#pragma unroll
      for (int nt = 0; nt < 2; ++nt)
#pragma unroll
        for (int i = 0; i < 16; ++i) cb[CBIDX(mt, nt, i)] += res[mt * 2 + nt][i] - RBIAS;
  }
  __syncthreads();

  // ---- cooperative x16 store ----
  const float4* cbv = (const float4*)cb;
  const int row = tid >> 2, c4 = tid & 3;
  float* orow = out + (size_t)(mblk * 64 + row) * N_TOT + nblk * 64;
#pragma unroll
  for (int p = 0; p < 4; ++p) {
    float4 vv = cbv[row * 16 + c4 + 4 * p];
    vv.x *= 16.0f; vv.y *= 16.0f; vv.z *= 16.0f; vv.w *= 16.0f;
    *(float4*)&orow[(c4 + 4 * p) * 4] = vv;
  }
}

extern "C" void kernel_launch(void* const* d_in, const int* in_sizes, int n_in,
                              void* d_out, int out_size, void* d_ws, size_t ws_size,
                              hipStream_t stream)
{
  const float* input  = (const float*)d_in[0];
  const float* weight = (const float*)d_in[1];
  const float* vmap   = (const float*)d_in[2];
  const float* wmap   = (const float*)d_in[3];
  float* out = (float*)d_out;

  u16* XHL = (u16*)d_ws;                         // 8MB (4M u16)
  u16* WHL = XHL + 4 * 1024 * 1024;              // 4MB   (ws use: 12MB total)

  presplit<<<1024, 256, 0, stream>>>(input, weight, vmap, wmap, XHL, WHL);

  opu_main<<<512, 256, 0, stream>>>(XHL, WHL, out);
}